// Round 1
// 587.162 us; speedup vs baseline: 1.0095x; 1.0095x over previous
//
#include <hip/hip_runtime.h>

#define NV 20000          // vertices
#define NE 4096           // hyperedges
#define FT 128            // features
#define NW_E 128          // u32 words per packed vertex row  (E/32)
#define NW_V 625          // real u32 words per packedT edge row (N/32)
#define PT_STRIDE 632     // padded packedT row stride (prefetch may read past word 625)
#define NKC2 157          // 128-wide n-chunks (157*128 = 20096)
#define K_TOT 20096

typedef __attribute__((ext_vector_type(8))) short short8v;   // 8 bf16 — MFMA A/B frag
typedef __attribute__((ext_vector_type(4))) float float4v;   // 4 fp32 — MFMA C/D frag

__device__ __forceinline__ unsigned short f2bf(float f) {    // fp32 -> bf16 RNE
    unsigned u = __float_as_uint(f);
    u += 0x7FFFu + ((u >> 16) & 1u);
    return (unsigned short)(u >> 16);
}
// LDS tile: rows of 128 bf16 (256B), 16B chunks XOR-swizzled by row (c ^ r&15).
// MFMA-phase b128 reads: 16 lanes hit 16 distinct chunk slots -> 2-way max (free).
__device__ __forceinline__ int lds_off(int r, int c) {
    return r * 256 + ((c ^ (r & 15)) << 4);
}
// 16B LUT entry: byte -> 8 bf16 in {0.0, 1.0}
__device__ __forceinline__ uint4 lut_entry(int t) {
    uint4 e;
    e.x = ((t & 1) ? 0x3F80u : 0u) | ((t & 2) ? 0x3F800000u : 0u);
    e.y = ((t & 4) ? 0x3F80u : 0u) | ((t & 8) ? 0x3F800000u : 0u);
    e.z = ((t & 16) ? 0x3F80u : 0u) | ((t & 32) ? 0x3F800000u : 0u);
    e.w = ((t & 64) ? 0x3F80u : 0u) | ((t & 128) ? 0x3F800000u : 0u);
    return e;
}
// async 16B global->LDS (DMA path, no VGPR roundtrip). LDS dest is wave-uniform
// base + lane*16; producers pre-swizzle the GLOBAL layout so linear copy == swizzled LDS.
__device__ __forceinline__ void cp16(void* l, const void* g) {
    __builtin_amdgcn_global_load_lds((__attribute__((address_space(1))) void*)g,
                                     (__attribute__((address_space(3))) void*)l, 16, 0, 0);
}

// ---------------- 1. pack H -> bits, COALESCED: wave = half row ----------------
// block = 2 rows (4 waves). Lane reads 128B contiguous; lane's 32 ints = 1 packed word.
// blocks 0..15 also zero de_cnt (consumed by k_btrans atomics, next dispatch).
__global__ __launch_bounds__(256) void k_pack(const int* __restrict__ H,
                                              unsigned* __restrict__ packed,
                                              float* __restrict__ dv,
                                              int* __restrict__ de_cnt) {
    __shared__ int cl[4];
    int t = threadIdx.x, wave = t >> 6, lane = t & 63;
    if (blockIdx.x < 16) de_cnt[blockIdx.x * 256 + t] = 0;
    int row = blockIdx.x * 2 + (wave >> 1);
    int half = wave & 1;
    const uint4* base = reinterpret_cast<const uint4*>(H) + (size_t)row * 1024 + half * 512 + lane * 8;
    unsigned m = 0;
#pragma unroll
    for (int i = 0; i < 8; ++i) {
        uint4 v = base[i];
        m |= (v.x ? 1u : 0u) << (i * 4 + 0);
        m |= (v.y ? 1u : 0u) << (i * 4 + 1);
        m |= (v.z ? 1u : 0u) << (i * 4 + 2);
        m |= (v.w ? 1u : 0u) << (i * 4 + 3);
    }
    packed[(size_t)row * NW_E + half * 64 + lane] = m;
    int c = __popc(m);
    for (int o = 32; o > 0; o >>= 1) c += __shfl_down(c, o, 64);
    if (lane == 0) cl[wave] = c;
    __syncthreads();
    if (t < 2) {
        int d = cl[t * 2] + cl[t * 2 + 1];
        dv[blockIdx.x * 2 + t] = d > 0 ? 1.0f / sqrtf((float)d) : 1.0f;
    }
}

// ---------------- 2. bit-transpose packed -> packedT + fused edge degree ----------------
__global__ __launch_bounds__(256) void k_btrans(const unsigned* __restrict__ packed,
                                                unsigned* __restrict__ packedT,
                                                int* __restrict__ de_cnt) {
    int lane = threadIdx.x & 63;
    int w = threadIdx.x >> 6;
    int ew = blockIdx.y * 4 + w;
    int n = blockIdx.x * 64 + lane;
    unsigned wv = (n < NV) ? packed[(size_t)n * NW_E + ew] : 0u;
    unsigned my = 0;
#pragma unroll
    for (int j = 0; j < 32; ++j) {
        unsigned long long m = __ballot(((wv >> j) & 1u) != 0);
        unsigned part = (lane < 32) ? (unsigned)m : (unsigned)(m >> 32);
        if ((lane & 31) == j) my = part;
    }
    int nw = blockIdx.x * 2 + (lane >> 5);
    int e = ew * 32 + (lane & 31);
    if (nw <= 625) packedT[(size_t)e * PT_STRIDE + nw] = my;
    // edge degree: lanes l and l+32 hold the two n-words of the same e
    int cnt = __popc(my);
    cnt += __shfl_down(cnt, 32, 64);
    if (lane < 32) atomicAdd(de_cnt + e, cnt);
}

// ---------------- 3. At[kc2][f][c-swz] = bf16(dv*X), PRE-SWIZZLED for cp16 ----------------
// 128-wide n-chunks; n >= 20000 zero-filled (makes packedT's unwritten pad words harmless).
__global__ __launch_bounds__(256) void k_mid(const float* __restrict__ X,
                                             const float* __restrict__ dv,
                                             unsigned short* __restrict__ At) {
    int t = threadIdx.x;
    int f = t & 127;
    int item = blockIdx.x * 2 + (t >> 7);     // 0..2511, 8 n each (2512*8 = 20096)
    int nbase = item * 8;
    unsigned short h[8];
#pragma unroll
    for (int i = 0; i < 8; ++i) {
        int n = nbase + i;
        float v = (n < NV) ? X[(size_t)n * FT + f] * dv[n] : 0.0f;
        h[i] = f2bf(v);
    }
    uint4 u;
    u.x = (unsigned)h[0] | ((unsigned)h[1] << 16);
    u.y = (unsigned)h[2] | ((unsigned)h[3] << 16);
    u.z = (unsigned)h[4] | ((unsigned)h[5] << 16);
    u.w = (unsigned)h[6] | ((unsigned)h[7] << 16);
    int kc2 = nbase >> 7;
    int c = (nbase >> 3) & 15;
    *reinterpret_cast<uint4*>(At + (size_t)kc2 * 16384 + f * 128 + ((c ^ (f & 15)) << 3)) = u;
}

// ---------------- 4. mm1: P[kp][f][e] = sum_n At[f][n] * H[n][e], split-K ----------------
// K-step 128 (half the barriers of the old 64). A via async global_load_lds from
// pre-swizzled At; B bits expanded via LDS LUT, one uint4 (=128 bits) per iter.
__global__ __launch_bounds__(256, 2) void k_mm1(const unsigned short* __restrict__ At,
                                                const unsigned* __restrict__ packedT,
                                                float* __restrict__ P, int chunkK) {
    __shared__ __align__(16) unsigned char sA[32768];   // 128 f x 128 n bf16 (swz)
    __shared__ __align__(16) unsigned char sB[32768];   // 128 e x 128 n bf16 (swz)
    __shared__ __align__(16) uint4 slut[256];
    int t = threadIdx.x;
    slut[t] = lut_entry(t);

    int et = blockIdx.x & 31, kp = blockIdx.x >> 5;
    int e0 = et * 128;
    int kbeg = kp * chunkK;
    int kend = kbeg + chunkK; if (kend > K_TOT) kend = K_TOT;
    int iters = (kend - kbeg) >> 7; if (iters < 0) iters = 0;

    float4v acc[4][4];
#pragma unroll
    for (int i = 0; i < 4; ++i)
#pragma unroll
        for (int j = 0; j < 4; ++j)
#pragma unroll
            for (int r = 0; r < 4; ++r) acc[i][j][r] = 0.0f;

    int wave = t >> 6, lane = t & 63;
    int wm0 = (wave & 1) * 64, wc0 = (wave >> 1) * 64;
    int r0 = lane & 15, q = lane >> 4;

    const uint4* brow4 = reinterpret_cast<const uint4*>(
        packedT + (size_t)(e0 + (t & 127)) * PT_STRIDE + (kbeg >> 5));
    uint4 bw;
    if (t < 128 && iters > 0) bw = *brow4;
    __syncthreads();   // LUT ready

    const char* gA = reinterpret_cast<const char*>(At) + (size_t)(kbeg >> 7) * 32768 + wave * 8192 + lane * 16;
    char* lA = reinterpret_cast<char*>(sA) + wave * 8192;

    for (int it = 0; it < iters; ++it) {
        // A: 32KB async DMA (each wave 8x1KB, linear dest = pre-swizzled layout)
        const char* g = gA + (size_t)it * 32768;
#pragma unroll
        for (int j = 0; j < 8; ++j) cp16(lA + j * 1024, g + j * 1024);
        // B: expand 4 words = 128 bits via LUT; prefetch next uint4 (pad keeps in-bounds)
        if (t < 128) {
            uint4 nxt = brow4[it + 1];
            unsigned wd[4] = {bw.x, bw.y, bw.z, bw.w};
#pragma unroll
            for (int c = 0; c < 16; ++c)
                *reinterpret_cast<uint4*>(sB + lds_off(t, c)) = slut[(wd[c >> 2] >> ((c & 3) * 8)) & 0xFF];
            bw = nxt;
        }
        __syncthreads();
#pragma unroll
        for (int ks = 0; ks < 4; ++ks) {
            short8v a[4], bb[4];
#pragma unroll
            for (int mi = 0; mi < 4; ++mi)
                a[mi] = *reinterpret_cast<const short8v*>(sA + lds_off(wm0 + mi * 16 + r0, ks * 4 + q));
#pragma unroll
            for (int ci = 0; ci < 4; ++ci)
                bb[ci] = *reinterpret_cast<const short8v*>(sB + lds_off(wc0 + ci * 16 + r0, ks * 4 + q));
#pragma unroll
            for (int mi = 0; mi < 4; ++mi)
#pragma unroll
                for (int ci = 0; ci < 4; ++ci)
                    acc[mi][ci] = __builtin_amdgcn_mfma_f32_16x16x32_bf16(a[mi], bb[ci], acc[mi][ci], 0, 0, 0);
        }
        __syncthreads();
    }
    float* Pp = P + (size_t)kp * (128 * 4096);
#pragma unroll
    for (int mi = 0; mi < 4; ++mi)
#pragma unroll
        for (int ci = 0; ci < 4; ++ci) {
            int f = wm0 + mi * 16 + q * 4;
            int e = e0 + wc0 + ci * 16 + r0;
#pragma unroll
            for (int r = 0; r < 4; ++r)
                Pp[(size_t)(f + r) * 4096 + e] = acc[mi][ci][r];
        }
}

// ---------------- 5. reduce split-K partials ----------------
__global__ __launch_bounds__(256) void k_reduce(const float4v* __restrict__ P,
                                                float4v* __restrict__ Tt, int S) {
    int i = blockIdx.x * 256 + threadIdx.x;   // 131072 float4 total
    float4v a = P[i];
    for (int p = 1; p < S; ++p) a += P[(size_t)p * 131072 + i];
    Tt[i] = a;
}

// ---------------- 6. Ut = bf16( de * (Tt^T W)^T ), PRE-SWIZZLED slabs for mm2 cp16 ----------------
// slab (qg,it) = 32 g-rows x 128 e, row-swizzled like lds_off.
__global__ __launch_bounds__(256) void k_ut(const float* __restrict__ Tt,
                                            const float* __restrict__ W,
                                            const int* __restrict__ de_cnt,
                                            unsigned short* __restrict__ Ut) {
    int t = threadIdx.x;
    int bx = blockIdx.x;
    int j = t & 63;
    int e = bx * 64 + j;
    int g0 = blockIdx.y * 16 + (t >> 6) * 4;
    float a0 = 0, a1 = 0, a2 = 0, a3 = 0;
    for (int f = 0; f < 128; ++f) {
        float tv = Tt[(size_t)f * 4096 + e];
        float4 wv = *reinterpret_cast<const float4*>(W + f * 128 + g0);
        a0 += tv * wv.x; a1 += tv * wv.y; a2 += tv * wv.z; a3 += tv * wv.w;
    }
    int cnt = de_cnt[e];
    float d = cnt > 0 ? 1.0f / (float)cnt : 1.0f;
    float av[4] = {a0, a1, a2, a3};
    int slabB = bx >> 1;                       // it = e>>7
    int chi = ((bx & 1) << 3) | (j >> 3);      // chunk within 128-e row
    int pos = j & 7;
#pragma unroll
    for (int k = 0; k < 4; ++k) {
        int g = g0 + k;
        int qg = g >> 5, gr = g & 31;
        Ut[(size_t)(qg * 32 + slabB) * 4096 + gr * 128 + ((chi ^ (gr & 15)) << 3) + pos] = f2bf(av[k] * d);
    }
}

// ---------------- 7. mm2: out[n][g] = dv[n]*sum_e H[n][e]*U[g][e] + bias[g] ----------------
// K-step 128, 32 iters (half the barriers). A bits via LDS LUT (waves 0,1);
// B via async global_load_lds from pre-swizzled Ut slabs (waves 2,3).
__global__ __launch_bounds__(256, 3) void k_mm2(const unsigned* __restrict__ packed,
                                                const unsigned short* __restrict__ Ut,
                                                const float* __restrict__ dv,
                                                const float* __restrict__ bias,
                                                float* __restrict__ out) {
    __shared__ __align__(16) unsigned char sA[32768];   // 128 n x 128 e bf16 (swz)
    __shared__ __align__(16) unsigned char sB[8192];    //  32 g x 128 e bf16 (swz)
    __shared__ __align__(16) uint4 slut[256];
    int t = threadIdx.x;
    slut[t] = lut_entry(t);

    int mt = blockIdx.x >> 2, qg = blockIdx.x & 3;
    int n0 = mt * 128, g0 = qg * 32;

    float4v acc[4];
#pragma unroll
    for (int i = 0; i < 4; ++i)
#pragma unroll
        for (int r = 0; r < 4; ++r) acc[i][r] = 0.0f;

    int wave = t >> 6, lane = t & 63;
    int wm0 = (wave & 1) * 64, wc0 = (wave >> 1) * 16;
    int r0 = lane & 15, q = lane >> 4;

    const uint4* arow4 = reinterpret_cast<const uint4*>(packed + (size_t)(n0 + (t & 127)) * NW_E);
    uint4 aw;
    if (t < 128) aw = *arow4;   // rows >= NV read in-ws garbage; outputs guarded
    __syncthreads();   // LUT ready

    int wb = wave & 1;
    const char* gB = reinterpret_cast<const char*>(Ut) + (size_t)(qg * 32) * 8192 + wb * 4096 + lane * 16;
    char* lB = reinterpret_cast<char*>(sB) + wb * 4096;

    for (int it = 0; it < 32; ++it) {
        if (t < 128) {
            uint4 nxt = arow4[it + 1];          // 16B over-read at it=31 lands in ws, never consumed
            unsigned wd[4] = {aw.x, aw.y, aw.z, aw.w};
#pragma unroll
            for (int c = 0; c < 16; ++c)
                *reinterpret_cast<uint4*>(sA + lds_off(t, c)) = slut[(wd[c >> 2] >> ((c & 3) * 8)) & 0xFF];
            aw = nxt;
        } else {
            const char* g = gB + (size_t)it * 8192;
#pragma unroll
            for (int j = 0; j < 4; ++j) cp16(lB + j * 1024, g + j * 1024);
        }
        __syncthreads();
#pragma unroll
        for (int ks = 0; ks < 4; ++ks) {
            short8v a[4], bb;
#pragma unroll
            for (int mi = 0; mi < 4; ++mi)
                a[mi] = *reinterpret_cast<const short8v*>(sA + lds_off(wm0 + mi * 16 + r0, ks * 4 + q));
            bb = *reinterpret_cast<const short8v*>(sB + lds_off(wc0 + r0, ks * 4 + q));
#pragma unroll
            for (int mi = 0; mi < 4; ++mi)
                acc[mi] = __builtin_amdgcn_mfma_f32_16x16x32_bf16(a[mi], bb, acc[mi], 0, 0, 0);
        }
        __syncthreads();
    }
    {
        int g = g0 + wc0 + r0;
        float bg = bias[g];
#pragma unroll
        for (int mi = 0; mi < 4; ++mi) {
#pragma unroll
            for (int r = 0; r < 4; ++r) {
                int n = n0 + wm0 + mi * 16 + q * 4 + r;
                if (n < NV) out[(size_t)n * 128 + g] = dv[n] * acc[mi][r] + bg;
            }
        }
    }
}

extern "C" void kernel_launch(void* const* d_in, const int* in_sizes, int n_in,
                              void* d_out, int out_size, void* d_ws, size_t ws_size,
                              hipStream_t stream) {
    const float* X    = (const float*)d_in[0];
    const int*   H    = (const int*)d_in[1];
    const float* W    = (const float*)d_in[2];
    const float* bias = (const float*)d_in[3];
    float* out = (float*)d_out;

    char* ws = (char*)d_ws;
    size_t off = 0;
    auto alloc = [&](size_t sz) { char* p = ws + off; off += (sz + 255) & ~(size_t)255; return p; };
    unsigned*       packed  = (unsigned*)alloc((size_t)NV * NW_E * 4);           // 10.24 MB
    unsigned*       packedT = (unsigned*)alloc((size_t)NE * PT_STRIDE * 4);      // 10.35 MB
    unsigned short* At      = (unsigned short*)alloc((size_t)NKC2 * 16384 * 2);  //  5.14 MB
    float*          Tt      = (float*)alloc((size_t)FT * NE * 4);                //  2.10 MB
    unsigned short* Ut      = (unsigned short*)alloc((size_t)FT * NE * 2);       //  1.05 MB
    float*          dv      = (float*)alloc((size_t)NV * 4);
    int*            de_cnt  = (int*)alloc((size_t)NE * 4);
    size_t fixed = off;

    long long avail = (long long)ws_size - (long long)fixed;
    int S = (int)(avail / (128LL * 4096 * 4));
    if (S > 16) S = 16;
    if (S < 1) S = 1;
    float* P1 = (float*)(ws + fixed);
    int chunkK = ((NKC2 + S - 1) / S) * 128;

    k_pack  <<<NV / 2, 256, 0, stream>>>(H, packed, dv, de_cnt);
    k_btrans<<<dim3(313, 32), 256, 0, stream>>>(packed, packedT, de_cnt);
    k_mid   <<<1256, 256, 0, stream>>>(X, dv, At);
    k_mm1   <<<32 * S, 256, 0, stream>>>(At, packedT, P1, chunkK);
    k_reduce<<<512, 256, 0, stream>>>((const float4v*)P1, (float4v*)Tt, S);
    k_ut    <<<dim3(64, 8), 256, 0, stream>>>(Tt, W, de_cnt, Ut);
    k_mm2   <<<628, 256, 0, stream>>>(packed, Ut, dv, bias, out);
}